// Round 1
// baseline (631.857 us; speedup 1.0000x reference)
//
#include <hip/hip_runtime.h>
#include <hip/hip_bf16.h>

// ---------------------------------------------------------------------------
// FakeFlexOlmoSparseMlp: top-2 MoE over 8 experts, H=1024, 8192 tokens.
// Sparse-equivalent computation: only the top-2 experts per token contribute
// (w[e]==0 elsewhere), so we bucket (token,expert) pairs by expert and run
// two grouped bf16 MFMA GEMMs (x@W1^T -> relu -> @W2^T), then scatter-add
// w*(y+b2) onto the residual.
// ---------------------------------------------------------------------------

#define HD   1024
#define NTOK 8192
#define NEXP 8
#define BM   128
#define BN   128
#define BK   64
#define LDSP 72      // padded LDS row stride (shorts): breaks 128B-stride bank aliasing
#define ZROW 8192    // sentinel row in x_bf16 filled with zeros (pad slots)
#define MAXP 17408   // 16384 pairs + 8*128 max padding = 136 tiles of 128

typedef __attribute__((ext_vector_type(8))) short  vshort8;
typedef __attribute__((ext_vector_type(4))) short  vshort4;
typedef __attribute__((ext_vector_type(4))) float  vfloat4;

__device__ __forceinline__ short bf16r(float f) {
    union { float f; unsigned u; } a; a.f = f;
    unsigned r = a.u + 0x7FFFu + ((a.u >> 16) & 1u);   // round-to-nearest-even
    return (short)(r >> 16);
}

// --- K1: zero meta, fill pair_token with the zero-row sentinel -------------
__global__ void init_kernel(int* counts, int* fill, int* pair_token) {
    int i = blockIdx.x * 256 + threadIdx.x;
    if (i < NEXP) { counts[i] = 0; fill[i] = 0; }
    if (i < MAXP) pair_token[i] = ZROW;
}

// --- K2: out = x (residual init); x_bf16 = bf16(x); row ZROW = zeros -------
__global__ void convert_kernel(const float* __restrict__ x,
                               float* __restrict__ out,
                               short* __restrict__ xb) {
    size_t i = ((size_t)blockIdx.x * 256 + threadIdx.x) * 4;
    if (i < (size_t)NTOK * HD) {
        vfloat4 v = *(const vfloat4*)(x + i);
        *(vfloat4*)(out + i) = v;
        vshort4 b;
        b.x = bf16r(v.x); b.y = bf16r(v.y); b.z = bf16r(v.z); b.w = bf16r(v.w);
        *(vshort4*)(xb + i) = b;
    } else {
        vshort4 z = {0, 0, 0, 0};
        *(vshort4*)(xb + i) = z;       // zero row for pad slots
    }
}

// --- K3: router: logits, softmax, top-2, renorm ----------------------------
__global__ __launch_bounds__(256) void router_kernel(
    const float* __restrict__ x, const float* __restrict__ rw,
    float* __restrict__ probs_out, int2* __restrict__ tok_top,
    float2* __restrict__ tok_w, int* __restrict__ counts) {
    __shared__ float rws[NEXP * HD];
    int t = threadIdx.x;
    for (int j = 0; j < 8; ++j) {
        int idx = j * 1024 + t * 4;
        *(vfloat4*)(rws + idx) = *(const vfloat4*)(rw + idx);
    }
    __syncthreads();
    int wave = t >> 6, lane = t & 63;
    int token = blockIdx.x * 4 + wave;
    const float* xr = x + (size_t)token * HD;
    float part[NEXP];
#pragma unroll
    for (int e = 0; e < NEXP; ++e) part[e] = 0.f;
    for (int j = 0; j < 4; ++j) {
        int off = j * 256 + lane * 4;
        vfloat4 xv = *(const vfloat4*)(xr + off);
#pragma unroll
        for (int e = 0; e < NEXP; ++e) {
            vfloat4 wv = *(const vfloat4*)(rws + e * HD + off);
            part[e] += xv.x * wv.x + xv.y * wv.y + xv.z * wv.z + xv.w * wv.w;
        }
    }
#pragma unroll
    for (int e = 0; e < NEXP; ++e)
        for (int off = 32; off; off >>= 1)
            part[e] += __shfl_xor(part[e], off, 64);
    if (lane == 0) {
        float m = part[0];
#pragma unroll
        for (int e = 1; e < NEXP; ++e) m = fmaxf(m, part[e]);
        float p[NEXP], s = 0.f;
#pragma unroll
        for (int e = 0; e < NEXP; ++e) { p[e] = expf(part[e] - m); s += p[e]; }
        float inv = 1.f / s;
#pragma unroll
        for (int e = 0; e < NEXP; ++e) {
            p[e] *= inv;
            probs_out[(size_t)token * NEXP + e] = p[e];
        }
        int i0 = 0;
#pragma unroll
        for (int e = 1; e < NEXP; ++e) if (p[e] > p[i0]) i0 = e;   // ties -> lowest idx
        int i1 = (i0 == 0) ? 1 : 0;
#pragma unroll
        for (int e = 0; e < NEXP; ++e) if (e != i0 && p[e] > p[i1]) i1 = e;
        float s2 = 1.f / (p[i0] + p[i1]);
        tok_top[token] = make_int2(i0, i1);
        tok_w[token]   = make_float2(p[i0] * s2, p[i1] * s2);
        atomicAdd(&counts[i0], 1);
        atomicAdd(&counts[i1], 1);
    }
}

// --- K4: per-expert padded offsets (segments multiple of 128) --------------
__global__ void offsets_kernel(const int* counts, int* offs) {
    if (threadIdx.x == 0 && blockIdx.x == 0) {
        int acc = 0;
        for (int e = 0; e < NEXP; ++e) {
            offs[e] = acc;
            acc += (counts[e] + 127) & ~127;
        }
        offs[NEXP] = acc;
    }
}

// --- K5: scatter pairs into expert buckets ---------------------------------
__global__ void scatter_kernel(const int2* __restrict__ tok_top,
                               const float2* __restrict__ tok_w,
                               const int* __restrict__ offs, int* fill,
                               int* __restrict__ pair_token,
                               float* __restrict__ pair_w) {
    int token = blockIdx.x * 256 + threadIdx.x;
    if (token >= NTOK) return;
    int2 ti = tok_top[token];
    float2 tw = tok_w[token];
    int p0 = atomicAdd(&fill[ti.x], 1);
    int s0 = offs[ti.x] + p0;
    pair_token[s0] = token; pair_w[s0] = tw.x;
    int p1 = atomicAdd(&fill[ti.y], 1);
    int s1 = offs[ti.y] + p1;
    pair_token[s1] = token; pair_w[s1] = tw.y;
}

// --- K6/K7: grouped NT-GEMM, 128x128 tile, 4 waves, mfma 16x16x32 bf16 -----
// MODE 0: A rows gathered via pair_token from x_bf16; epi relu(acc+b1) -> h1 bf16
// MODE 1: A rows = h1 slots directly; epi atomicAdd out += w*(acc+b2)
template <int MODE>
__global__ __launch_bounds__(256) void moe_gemm(
    const short* __restrict__ A, const float* __restrict__ Bw,
    const float* __restrict__ bias, const int* __restrict__ pair_token,
    const float* __restrict__ pair_w, const int* __restrict__ offs,
    short* __restrict__ h1_out, float* __restrict__ out) {
    __shared__ short sA[BM * LDSP];
    __shared__ short sB[BN * LDSP];

    const int row0 = blockIdx.x * BM;
    const int total = offs[NEXP];          // multiple of 128
    if (row0 >= total) return;
    int e = 0;
#pragma unroll
    for (int k = 0; k < NEXP - 1; ++k)
        if (offs[e + 1] <= row0) e++;

    const int t = threadIdx.x;
    const int wave = t >> 6, lane = t & 63;
    const int wm = wave >> 1, wn = wave & 1;
    const int quad = lane >> 4, l16 = lane & 15;
    const int col_base = blockIdx.y * BN;

    // A staging: round r: row = r*32 + (t>>3), 16B chunk (t&7)*8 shorts
    const int arow_local = t >> 3;
    const int acol = (t & 7) * 8;
    const short* aptr[4];
#pragma unroll
    for (int r = 0; r < 4; ++r) {
        int rit = r * 32 + arow_local;
        int row = (MODE == 0) ? pair_token[row0 + rit] : (row0 + rit);
        aptr[r] = A + (size_t)row * HD + acol;
    }
    // B staging: round j: row = j*16 + (t>>4), 4 floats at (t&15)*4
    const int brow = t >> 4;
    const int bcol = (t & 15) * 4;
    const float* bptr = Bw + (size_t)e * HD * HD + (size_t)(col_base + brow) * HD + bcol;

    vfloat4 acc[4][4];
#pragma unroll
    for (int i = 0; i < 4; ++i)
#pragma unroll
        for (int j = 0; j < 4; ++j)
            acc[i][j] = (vfloat4){0.f, 0.f, 0.f, 0.f};

    for (int k0 = 0; k0 < HD; k0 += BK) {
        __syncthreads();
#pragma unroll
        for (int r = 0; r < 4; ++r) {
            vshort8 v = *(const vshort8*)(aptr[r] + k0);
            *(vshort8*)(sA + (r * 32 + arow_local) * LDSP + acol) = v;
        }
#pragma unroll
        for (int j = 0; j < 8; ++j) {
            vfloat4 v = *(const vfloat4*)(bptr + (size_t)j * 16 * HD + k0);
            vshort4 b;
            b.x = bf16r(v.x); b.y = bf16r(v.y); b.z = bf16r(v.z); b.w = bf16r(v.w);
            *(vshort4*)(sB + (j * 16 + brow) * LDSP + bcol) = b;
        }
        __syncthreads();
#pragma unroll
        for (int s = 0; s < 2; ++s) {
            vshort8 af[4], bfr[4];
#pragma unroll
            for (int i = 0; i < 4; ++i)
                af[i] = *(const vshort8*)(sA + (wm * 64 + i * 16 + l16) * LDSP + s * 32 + quad * 8);
#pragma unroll
            for (int i = 0; i < 4; ++i)
                bfr[i] = *(const vshort8*)(sB + (wn * 64 + i * 16 + l16) * LDSP + s * 32 + quad * 8);
#pragma unroll
            for (int i = 0; i < 4; ++i)
#pragma unroll
                for (int j = 0; j < 4; ++j)
                    acc[i][j] = __builtin_amdgcn_mfma_f32_16x16x32_bf16(af[i], bfr[j], acc[i][j], 0, 0, 0);
        }
    }

    if (MODE == 0) {
#pragma unroll
        for (int j = 0; j < 4; ++j) {
            int col = col_base + wn * 64 + j * 16 + l16;
            float bv = bias[e * HD + col];
#pragma unroll
            for (int i = 0; i < 4; ++i) {
                int rbase = row0 + wm * 64 + i * 16 + quad * 4;
#pragma unroll
                for (int reg = 0; reg < 4; ++reg) {
                    float v = acc[i][j][reg] + bv;
                    v = v > 0.f ? v : 0.f;
                    h1_out[(size_t)(rbase + reg) * HD + col] = bf16r(v);
                }
            }
        }
    } else {
        int tok[4][4]; float wv[4][4];
#pragma unroll
        for (int i = 0; i < 4; ++i)
#pragma unroll
            for (int reg = 0; reg < 4; ++reg) {
                int r = row0 + wm * 64 + i * 16 + quad * 4 + reg;
                tok[i][reg] = pair_token[r];
                wv[i][reg] = pair_w[r];
            }
#pragma unroll
        for (int j = 0; j < 4; ++j) {
            int col = col_base + wn * 64 + j * 16 + l16;
            float bv = bias[e * HD + col];
#pragma unroll
            for (int i = 0; i < 4; ++i)
#pragma unroll
                for (int reg = 0; reg < 4; ++reg)
                    if (tok[i][reg] < ZROW)
                        atomicAdd(out + (size_t)tok[i][reg] * HD + col,
                                  wv[i][reg] * (acc[i][j][reg] + bv));
        }
    }
}

extern "C" void kernel_launch(void* const* d_in, const int* in_sizes, int n_in,
                              void* d_out, int out_size, void* d_ws, size_t ws_size,
                              hipStream_t stream) {
    const float* x  = (const float*)d_in[0];
    const float* rw = (const float*)d_in[1];
    const float* W1 = (const float*)d_in[2];
    const float* b1 = (const float*)d_in[3];
    const float* W2 = (const float*)d_in[4];
    const float* b2 = (const float*)d_in[5];
    float* out   = (float*)d_out;                // [8192,1024] residual+moe
    float* probs = out + (size_t)NTOK * HD;      // [8192,8]

    // workspace layout (~52.8 MB)
    char* ws = (char*)d_ws;
    short* xb = (short*)ws;            ws += (size_t)(NTOK + 1) * HD * 2;  // 16.78 MB (+zero row)
    short* h1 = (short*)ws;            ws += (size_t)MAXP * HD * 2;        // 35.65 MB
    int*   pair_token = (int*)ws;      ws += MAXP * 4;
    float* pair_w     = (float*)ws;    ws += MAXP * 4;
    int*   counts = (int*)ws;          ws += 256;
    int*   fill   = (int*)ws;          ws += 256;
    int*   offs   = (int*)ws;          ws += 256;
    int2*   tok_top = (int2*)ws;       ws += NTOK * 8;
    float2* tok_w   = (float2*)ws;     ws += NTOK * 8;

    init_kernel<<<MAXP / 256, 256, 0, stream>>>(counts, fill, pair_token);
    convert_kernel<<<(NTOK + 1) * HD / 4 / 256, 256, 0, stream>>>(x, out, xb);
    router_kernel<<<NTOK / 4, 256, 0, stream>>>(x, rw, probs, tok_top, tok_w, counts);
    offsets_kernel<<<1, 64, 0, stream>>>(counts, offs);
    scatter_kernel<<<NTOK / 256, 256, 0, stream>>>(tok_top, tok_w, offs, fill,
                                                   pair_token, pair_w);
    dim3 gg(MAXP / BM, HD / BN);   // 136 x 8, blocks past padded total exit early
    moe_gemm<0><<<gg, 256, 0, stream>>>(xb, W1, b1, pair_token, pair_w, offs, h1, nullptr);
    moe_gemm<1><<<gg, 256, 0, stream>>>(h1, W2, b2, pair_token, pair_w, offs, nullptr, out);
}

// Round 2
// 392.327 us; speedup vs baseline: 1.6105x; 1.6105x over previous
//
#include <hip/hip_runtime.h>
#include <hip/hip_bf16.h>

// ---------------------------------------------------------------------------
// FakeFlexOlmoSparseMlp: top-2 MoE over 8 experts, H=1024, 8192 tokens.
// R2: (a) LDS-aggregated histogram/rank atomics (R1 had 16K same-address
// global atomics in router+scatter = ~200us each); (b) one-shot fp32->bf16
// weight conversion (runtime ws_size-guarded) to strip VALU converts from
// the GEMM inner loop and halve B staging traffic.
// ---------------------------------------------------------------------------

#define HD   1024
#define NTOK 8192
#define NEXP 8
#define BM   128
#define BN   128
#define BK   64
#define LDSP 72      // padded LDS row stride (shorts)
#define ZROW 8192    // sentinel row in x_bf16 filled with zeros (pad slots)
#define MAXP 17408   // 16384 pairs + 8*128 max padding = 136 tiles of 128

typedef __attribute__((ext_vector_type(8))) short  vshort8;
typedef __attribute__((ext_vector_type(4))) short  vshort4;
typedef __attribute__((ext_vector_type(4))) float  vfloat4;

__device__ __forceinline__ short bf16r(float f) {
    union { float f; unsigned u; } a; a.f = f;
    unsigned r = a.u + 0x7FFFu + ((a.u >> 16) & 1u);   // round-to-nearest-even
    return (short)(r >> 16);
}

// --- K1: zero meta, fill pair_token with the zero-row sentinel -------------
__global__ void init_kernel(int* counts, int* fill, int* pair_token) {
    int i = blockIdx.x * 256 + threadIdx.x;
    if (i < NEXP) { counts[i] = 0; fill[i] = 0; }
    if (i < MAXP) pair_token[i] = ZROW;
}

// --- K2: out = x (residual init); x_bf16 = bf16(x); row ZROW = zeros -------
__global__ void convert_kernel(const float* __restrict__ x,
                               float* __restrict__ out,
                               short* __restrict__ xb) {
    size_t i = ((size_t)blockIdx.x * 256 + threadIdx.x) * 4;
    if (i < (size_t)NTOK * HD) {
        vfloat4 v = *(const vfloat4*)(x + i);
        *(vfloat4*)(out + i) = v;
        vshort4 b;
        b.x = bf16r(v.x); b.y = bf16r(v.y); b.z = bf16r(v.z); b.w = bf16r(v.w);
        *(vshort4*)(xb + i) = b;
    } else {
        vshort4 z = {0, 0, 0, 0};
        *(vshort4*)(xb + i) = z;       // zero row for pad slots
    }
}

// --- K2b: fp32 weights -> bf16 (8 elems/thread) ----------------------------
__global__ void convw_kernel(const float* __restrict__ src,
                             short* __restrict__ dst) {
    size_t i = ((size_t)blockIdx.x * 256 + threadIdx.x) * 8;
    vfloat4 a = *(const vfloat4*)(src + i);
    vfloat4 b = *(const vfloat4*)(src + i + 4);
    vshort8 o;
    o[0] = bf16r(a.x); o[1] = bf16r(a.y); o[2] = bf16r(a.z); o[3] = bf16r(a.w);
    o[4] = bf16r(b.x); o[5] = bf16r(b.y); o[6] = bf16r(b.z); o[7] = bf16r(b.w);
    *(vshort8*)(dst + i) = o;
}

// --- K3: router: logits, softmax, top-2, renorm; LDS-aggregated counts -----
// 64 tokens per block (wave-per-token, 16 iterations) amortizes the 32KB
// rw LDS stage; per-block LDS histogram -> 8 global atomics per block.
__global__ __launch_bounds__(256) void router_kernel(
    const float* __restrict__ x, const float* __restrict__ rw,
    float* __restrict__ probs_out, int2* __restrict__ tok_top,
    float2* __restrict__ tok_w, int* __restrict__ counts) {
    __shared__ float rws[NEXP * HD];
    __shared__ int hist[NEXP];
    int t = threadIdx.x;
    if (t < NEXP) hist[t] = 0;
    for (int j = 0; j < 8; ++j) {
        int idx = j * 1024 + t * 4;
        *(vfloat4*)(rws + idx) = *(const vfloat4*)(rw + idx);
    }
    __syncthreads();
    int wave = t >> 6, lane = t & 63;
    for (int it = 0; it < 16; ++it) {
        int token = blockIdx.x * 64 + it * 4 + wave;
        const float* xr = x + (size_t)token * HD;
        float part[NEXP];
#pragma unroll
        for (int e = 0; e < NEXP; ++e) part[e] = 0.f;
        for (int j = 0; j < 4; ++j) {
            int off = j * 256 + lane * 4;
            vfloat4 xv = *(const vfloat4*)(xr + off);
#pragma unroll
            for (int e = 0; e < NEXP; ++e) {
                vfloat4 wv = *(const vfloat4*)(rws + e * HD + off);
                part[e] += xv.x * wv.x + xv.y * wv.y + xv.z * wv.z + xv.w * wv.w;
            }
        }
#pragma unroll
        for (int e = 0; e < NEXP; ++e)
            for (int off = 32; off; off >>= 1)
                part[e] += __shfl_xor(part[e], off, 64);
        if (lane == 0) {
            float m = part[0];
#pragma unroll
            for (int e = 1; e < NEXP; ++e) m = fmaxf(m, part[e]);
            float p[NEXP], s = 0.f;
#pragma unroll
            for (int e = 0; e < NEXP; ++e) { p[e] = expf(part[e] - m); s += p[e]; }
            float inv = 1.f / s;
#pragma unroll
            for (int e = 0; e < NEXP; ++e) {
                p[e] *= inv;
                probs_out[(size_t)token * NEXP + e] = p[e];
            }
            int i0 = 0;
#pragma unroll
            for (int e = 1; e < NEXP; ++e) if (p[e] > p[i0]) i0 = e;  // ties -> lowest idx
            int i1 = (i0 == 0) ? 1 : 0;
#pragma unroll
            for (int e = 0; e < NEXP; ++e) if (e != i0 && p[e] > p[i1]) i1 = e;
            float s2 = 1.f / (p[i0] + p[i1]);
            tok_top[token] = make_int2(i0, i1);
            tok_w[token]   = make_float2(p[i0] * s2, p[i1] * s2);
            atomicAdd(&hist[i0], 1);     // LDS atomic
            atomicAdd(&hist[i1], 1);
        }
    }
    __syncthreads();
    if (t < NEXP) atomicAdd(&counts[t], hist[t]);   // 8 global atomics/block
}

// --- K4: per-expert padded offsets (segments multiple of 128) --------------
__global__ void offsets_kernel(const int* counts, int* offs) {
    if (threadIdx.x == 0 && blockIdx.x == 0) {
        int acc = 0;
        for (int e = 0; e < NEXP; ++e) {
            offs[e] = acc;
            acc += (counts[e] + 127) & ~127;
        }
        offs[NEXP] = acc;
    }
}

// --- K5: scatter pairs into expert buckets (LDS rank + 8 global atomics) ---
__global__ __launch_bounds__(256) void scatter_kernel(
    const int2* __restrict__ tok_top, const float2* __restrict__ tok_w,
    const int* __restrict__ offs, int* fill,
    int* __restrict__ pair_token, float* __restrict__ pair_w) {
    __shared__ int lhist[NEXP];
    __shared__ int lbase[NEXP];
    int t = threadIdx.x;
    if (t < NEXP) lhist[t] = 0;
    __syncthreads();
    int token = blockIdx.x * 256 + t;
    int2 ti = tok_top[token];
    float2 tw = tok_w[token];
    int r0 = atomicAdd(&lhist[ti.x], 1);    // LDS atomics: intra-block rank
    int r1 = atomicAdd(&lhist[ti.y], 1);
    __syncthreads();
    if (t < NEXP) lbase[t] = atomicAdd(&fill[t], lhist[t]);  // 8 global/block
    __syncthreads();
    int s0 = offs[ti.x] + lbase[ti.x] + r0;
    pair_token[s0] = token; pair_w[s0] = tw.x;
    int s1 = offs[ti.y] + lbase[ti.y] + r1;
    pair_token[s1] = token; pair_w[s1] = tw.y;
}

// --- K6/K7: grouped NT-GEMM, 128x128 tile, 4 waves, mfma 16x16x32 bf16 -----
// MODE 0: A rows gathered via pair_token from x_bf16; epi relu(acc+b1) -> h1
// MODE 1: A rows = h1 slots directly; epi atomicAdd out += w*(acc+b2)
// BBF 1: B is pre-converted bf16; BBF 0: B is fp32, convert during staging.
template <int MODE, int BBF>
__global__ __launch_bounds__(256) void moe_gemm(
    const short* __restrict__ A, const void* __restrict__ Bw,
    const float* __restrict__ bias, const int* __restrict__ pair_token,
    const float* __restrict__ pair_w, const int* __restrict__ offs,
    short* __restrict__ h1_out, float* __restrict__ out) {
    __shared__ short sA[BM * LDSP];
    __shared__ short sB[BN * LDSP];

    const int row0 = blockIdx.x * BM;
    const int total = offs[NEXP];          // multiple of 128
    if (row0 >= total) return;
    int e = 0;
#pragma unroll
    for (int k = 0; k < NEXP - 1; ++k)
        if (offs[e + 1] <= row0) e++;

    const int t = threadIdx.x;
    const int wave = t >> 6, lane = t & 63;
    const int wm = wave >> 1, wn = wave & 1;
    const int quad = lane >> 4, l16 = lane & 15;
    const int col_base = blockIdx.y * BN;

    // A staging: round r: row = r*32 + (t>>3), 16B chunk (t&7)*8 shorts
    const int arow_local = t >> 3;
    const int acol = (t & 7) * 8;
    const short* aptr[4];
#pragma unroll
    for (int r = 0; r < 4; ++r) {
        int rit = r * 32 + arow_local;
        int row = (MODE == 0) ? pair_token[row0 + rit] : (row0 + rit);
        aptr[r] = A + (size_t)row * HD + acol;
    }
    // B staging pointers
    const float* bptrf = (const float*)Bw + (size_t)e * HD * HD +
                         (size_t)(col_base + (t >> 4)) * HD + (t & 15) * 4;
    const short* bptrh = (const short*)Bw + (size_t)e * HD * HD +
                         (size_t)(col_base + arow_local) * HD + acol;

    vfloat4 acc[4][4];
#pragma unroll
    for (int i = 0; i < 4; ++i)
#pragma unroll
        for (int j = 0; j < 4; ++j)
            acc[i][j] = (vfloat4){0.f, 0.f, 0.f, 0.f};

    for (int k0 = 0; k0 < HD; k0 += BK) {
        __syncthreads();
#pragma unroll
        for (int r = 0; r < 4; ++r) {
            vshort8 v = *(const vshort8*)(aptr[r] + k0);
            *(vshort8*)(sA + (r * 32 + arow_local) * LDSP + acol) = v;
        }
        if (BBF) {
#pragma unroll
            for (int r = 0; r < 4; ++r) {
                vshort8 v = *(const vshort8*)(bptrh + (size_t)(r * 32) * HD + k0);
                *(vshort8*)(sB + (r * 32 + arow_local) * LDSP + acol) = v;
            }
        } else {
#pragma unroll
            for (int j = 0; j < 8; ++j) {
                vfloat4 v = *(const vfloat4*)(bptrf + (size_t)j * 16 * HD + k0);
                vshort4 b;
                b.x = bf16r(v.x); b.y = bf16r(v.y); b.z = bf16r(v.z); b.w = bf16r(v.w);
                *(vshort4*)(sB + (j * 16 + (t >> 4)) * LDSP + (t & 15) * 4) = b;
            }
        }
        __syncthreads();
#pragma unroll
        for (int s = 0; s < 2; ++s) {
            vshort8 af[4], bfr[4];
#pragma unroll
            for (int i = 0; i < 4; ++i)
                af[i] = *(const vshort8*)(sA + (wm * 64 + i * 16 + l16) * LDSP + s * 32 + quad * 8);
#pragma unroll
            for (int i = 0; i < 4; ++i)
                bfr[i] = *(const vshort8*)(sB + (wn * 64 + i * 16 + l16) * LDSP + s * 32 + quad * 8);
#pragma unroll
            for (int i = 0; i < 4; ++i)
#pragma unroll
                for (int j = 0; j < 4; ++j)
                    acc[i][j] = __builtin_amdgcn_mfma_f32_16x16x32_bf16(af[i], bfr[j], acc[i][j], 0, 0, 0);
        }
    }

    if (MODE == 0) {
#pragma unroll
        for (int j = 0; j < 4; ++j) {
            int col = col_base + wn * 64 + j * 16 + l16;
            float bv = bias[e * HD + col];
#pragma unroll
            for (int i = 0; i < 4; ++i) {
                int rbase = row0 + wm * 64 + i * 16 + quad * 4;
#pragma unroll
                for (int reg = 0; reg < 4; ++reg) {
                    float v = acc[i][j][reg] + bv;
                    v = v > 0.f ? v : 0.f;
                    h1_out[(size_t)(rbase + reg) * HD + col] = bf16r(v);
                }
            }
        }
    } else {
        int tok[4][4]; float wv[4][4];
#pragma unroll
        for (int i = 0; i < 4; ++i)
#pragma unroll
            for (int reg = 0; reg < 4; ++reg) {
                int r = row0 + wm * 64 + i * 16 + quad * 4 + reg;
                tok[i][reg] = pair_token[r];
                wv[i][reg] = pair_w[r];
            }
#pragma unroll
        for (int j = 0; j < 4; ++j) {
            int col = col_base + wn * 64 + j * 16 + l16;
            float bv = bias[e * HD + col];
#pragma unroll
            for (int i = 0; i < 4; ++i)
#pragma unroll
                for (int reg = 0; reg < 4; ++reg)
                    if (tok[i][reg] < ZROW)
                        atomicAdd(out + (size_t)tok[i][reg] * HD + col,
                                  wv[i][reg] * (acc[i][j][reg] + bv));
        }
    }
}

extern "C" void kernel_launch(void* const* d_in, const int* in_sizes, int n_in,
                              void* d_out, int out_size, void* d_ws, size_t ws_size,
                              hipStream_t stream) {
    const float* x  = (const float*)d_in[0];
    const float* rw = (const float*)d_in[1];
    const float* W1 = (const float*)d_in[2];
    const float* b1 = (const float*)d_in[3];
    const float* W2 = (const float*)d_in[4];
    const float* b2 = (const float*)d_in[5];
    float* out   = (float*)d_out;                // [8192,1024] residual+moe
    float* probs = out + (size_t)NTOK * HD;      // [8192,8]

    // workspace layout
    char* ws = (char*)d_ws;
    short* xb = (short*)ws;            ws += (size_t)(NTOK + 1) * HD * 2;  // 16.78 MB
    short* h1 = (short*)ws;            ws += (size_t)MAXP * HD * 2;        // 35.65 MB
    int*   pair_token = (int*)ws;      ws += MAXP * 4;
    float* pair_w     = (float*)ws;    ws += MAXP * 4;
    int*   counts = (int*)ws;          ws += 256;
    int*   fill   = (int*)ws;          ws += 256;
    int*   offs   = (int*)ws;          ws += 256;
    int2*   tok_top = (int2*)ws;       ws += NTOK * 8;
    float2* tok_w   = (float2*)ws;     ws += NTOK * 8;
    short* w1b = (short*)ws;           ws += (size_t)NEXP * HD * HD * 2;   // 16.78 MB
    short* w2b = (short*)ws;           ws += (size_t)NEXP * HD * HD * 2;   // 16.78 MB
    const bool use_bf16w = ws_size >= (size_t)((char*)ws - (char*)d_ws);

    init_kernel<<<MAXP / 256, 256, 0, stream>>>(counts, fill, pair_token);
    convert_kernel<<<(NTOK + 1) * HD / 4 / 256, 256, 0, stream>>>(x, out, xb);
    router_kernel<<<NTOK / 64, 256, 0, stream>>>(x, rw, probs, tok_top, tok_w, counts);
    offsets_kernel<<<1, 64, 0, stream>>>(counts, offs);
    scatter_kernel<<<NTOK / 256, 256, 0, stream>>>(tok_top, tok_w, offs, fill,
                                                   pair_token, pair_w);
    dim3 gg(MAXP / BM, HD / BN);   // 136 x 8, blocks past padded total exit early
    if (use_bf16w) {
        int cg = NEXP * HD * HD / 8 / 256;   // 4096 blocks
        convw_kernel<<<cg, 256, 0, stream>>>(W1, w1b);
        convw_kernel<<<cg, 256, 0, stream>>>(W2, w2b);
        moe_gemm<0, 1><<<gg, 256, 0, stream>>>(xb, w1b, b1, pair_token, pair_w, offs, h1, nullptr);
        moe_gemm<1, 1><<<gg, 256, 0, stream>>>(h1, w2b, b2, pair_token, pair_w, offs, nullptr, out);
    } else {
        moe_gemm<0, 0><<<gg, 256, 0, stream>>>(xb, W1, b1, pair_token, pair_w, offs, h1, nullptr);
        moe_gemm<1, 0><<<gg, 256, 0, stream>>>(h1, W2, b2, pair_token, pair_w, offs, nullptr, out);
    }
}

// Round 3
// 336.367 us; speedup vs baseline: 1.8785x; 1.1664x over previous
//
#include <hip/hip_runtime.h>
#include <hip/hip_bf16.h>

// ---------------------------------------------------------------------------
// FakeFlexOlmoSparseMlp: top-2 MoE over 8 experts, H=1024, 8192 tokens.
// R3: async global_load_lds(16B) staging into MFMA-fragment-ordered LDS
// chunks (1KB = one wave-load = one 16x32 fragment set). Weights pre-swizzled
// into chunk order; h1 stored chunk-ordered via LDS transpose in gemm1's
// epilogue. Fixes R2's latency-bound staging (MfmaUtil 10%, all pipes idle).
// Router fused with residual-copy/bf16-cast; W1+W2 conversion fused.
// ---------------------------------------------------------------------------

#define HD   1024
#define NTOK 8192
#define NEXP 8
#define BM   128
#define BN   128
#define BK   64
#define ZROW 8192     // sentinel row in x_bf16 filled with zeros (pad slots)
#define MAXP 17408    // 16384 pairs + 8*128 max padding = 136 tiles of 128
#define EP_LDSW 136   // epilogue LDS row stride (shorts); 272B = 16B-aligned

typedef __attribute__((ext_vector_type(8))) short  vshort8;
typedef __attribute__((ext_vector_type(4))) short  vshort4;
typedef __attribute__((ext_vector_type(4))) float  vfloat4;

typedef __attribute__((address_space(1))) const unsigned gas_uint;
typedef __attribute__((address_space(3))) unsigned       las_uint;

__device__ __forceinline__ void gld16(const void* g, void* l) {
    // async global->LDS, 16B/lane; LDS dest = wave-uniform base + lane*16
    __builtin_amdgcn_global_load_lds((gas_uint*)g, (las_uint*)l, 16, 0, 0);
}

__device__ __forceinline__ short bf16r(float f) {
    union { float f; unsigned u; } a; a.f = f;
    unsigned r = a.u + 0x7FFFu + ((a.u >> 16) & 1u);   // round-to-nearest-even
    return (short)(r >> 16);
}

// --- K1: zero meta, pair_token -> ZROW sentinel, zero the ZROW row ---------
__global__ void init_kernel(int* counts, int* fill, int* pair_token, short* xb) {
    int i = blockIdx.x * 256 + threadIdx.x;
    if (i < NEXP) { counts[i] = 0; fill[i] = 0; }
    if (i < MAXP) pair_token[i] = ZROW;
    if (i < HD / 8) {
        vshort8 z = {0, 0, 0, 0, 0, 0, 0, 0};
        *(vshort8*)(xb + (size_t)ZROW * HD + i * 8) = z;
    }
}

// --- K2: router fused with residual-copy + bf16 cast -----------------------
// 32 tokens/block (wave-per-token, 8 iters), 256 blocks. Writes out=x,
// xb=bf16(x), probs, top2, LDS-aggregated expert counts.
__global__ __launch_bounds__(256) void router_kernel(
    const float* __restrict__ x, const float* __restrict__ rw,
    float* __restrict__ out, short* __restrict__ xb,
    float* __restrict__ probs_out, int2* __restrict__ tok_top,
    float2* __restrict__ tok_w, int* __restrict__ counts) {
    __shared__ float rws[NEXP * HD];
    __shared__ int hist[NEXP];
    int t = threadIdx.x;
    if (t < NEXP) hist[t] = 0;
    for (int j = 0; j < 8; ++j) {
        int idx = j * 1024 + t * 4;
        *(vfloat4*)(rws + idx) = *(const vfloat4*)(rw + idx);
    }
    __syncthreads();
    int wave = t >> 6, lane = t & 63;
    for (int it = 0; it < 8; ++it) {
        int token = blockIdx.x * 32 + it * 4 + wave;
        const float* xr = x + (size_t)token * HD;
        float part[NEXP];
#pragma unroll
        for (int e = 0; e < NEXP; ++e) part[e] = 0.f;
        for (int j = 0; j < 4; ++j) {
            int off = j * 256 + lane * 4;
            vfloat4 xv = *(const vfloat4*)(xr + off);
            *(vfloat4*)(out + (size_t)token * HD + off) = xv;   // residual init
            vshort4 bq;
            bq.x = bf16r(xv.x); bq.y = bf16r(xv.y); bq.z = bf16r(xv.z); bq.w = bf16r(xv.w);
            *(vshort4*)(xb + (size_t)token * HD + off) = bq;
#pragma unroll
            for (int e = 0; e < NEXP; ++e) {
                vfloat4 wv = *(const vfloat4*)(rws + e * HD + off);
                part[e] += xv.x * wv.x + xv.y * wv.y + xv.z * wv.z + xv.w * wv.w;
            }
        }
#pragma unroll
        for (int e = 0; e < NEXP; ++e)
            for (int off = 32; off; off >>= 1)
                part[e] += __shfl_xor(part[e], off, 64);
        if (lane == 0) {
            float m = part[0];
#pragma unroll
            for (int e = 1; e < NEXP; ++e) m = fmaxf(m, part[e]);
            float p[NEXP], s = 0.f;
#pragma unroll
            for (int e = 0; e < NEXP; ++e) { p[e] = expf(part[e] - m); s += p[e]; }
            float inv = 1.f / s;
#pragma unroll
            for (int e = 0; e < NEXP; ++e) {
                p[e] *= inv;
                probs_out[(size_t)token * NEXP + e] = p[e];
            }
            int i0 = 0;
#pragma unroll
            for (int e = 1; e < NEXP; ++e) if (p[e] > p[i0]) i0 = e;  // ties -> lowest idx
            int i1 = (i0 == 0) ? 1 : 0;
#pragma unroll
            for (int e = 0; e < NEXP; ++e) if (e != i0 && p[e] > p[i1]) i1 = e;
            float s2 = 1.f / (p[i0] + p[i1]);
            tok_top[token] = make_int2(i0, i1);
            tok_w[token]   = make_float2(p[i0] * s2, p[i1] * s2);
            atomicAdd(&hist[i0], 1);
            atomicAdd(&hist[i1], 1);
        }
    }
    __syncthreads();
    if (t < NEXP) atomicAdd(&counts[t], hist[t]);
}

// --- K3: per-expert padded offsets (segments multiple of 128) --------------
__global__ void offsets_kernel(const int* counts, int* offs) {
    if (threadIdx.x == 0 && blockIdx.x == 0) {
        int acc = 0;
        for (int e = 0; e < NEXP; ++e) {
            offs[e] = acc;
            acc += (counts[e] + 127) & ~127;
        }
        offs[NEXP] = acc;
    }
}

// --- K4: scatter pairs into expert buckets (LDS rank + 8 global atomics) ---
__global__ __launch_bounds__(256) void scatter_kernel(
    const int2* __restrict__ tok_top, const float2* __restrict__ tok_w,
    const int* __restrict__ offs, int* fill,
    int* __restrict__ pair_token, float* __restrict__ pair_w) {
    __shared__ int lhist[NEXP];
    __shared__ int lbase[NEXP];
    int t = threadIdx.x;
    if (t < NEXP) lhist[t] = 0;
    __syncthreads();
    int token = blockIdx.x * 256 + t;
    int2 ti = tok_top[token];
    float2 tw = tok_w[token];
    int r0 = atomicAdd(&lhist[ti.x], 1);
    int r1 = atomicAdd(&lhist[ti.y], 1);
    __syncthreads();
    if (t < NEXP) lbase[t] = atomicAdd(&fill[t], lhist[t]);
    __syncthreads();
    int s0 = offs[ti.x] + lbase[ti.x] + r0;
    pair_token[s0] = token; pair_w[s0] = tw.x;
    int s1 = offs[ti.y] + lbase[ti.y] + r1;
    pair_token[s1] = token; pair_w[s1] = tw.y;
}

// --- K5: fp32 W1+W2 -> bf16 in MFMA-fragment chunk order -------------------
// Chunk C = ((e*64 + ng)*32 + kc): 64 lanes x 16B; lane l holds
// W[e][ng*16 + (l&15)][kc*32 + (l>>4)*8 .. +7]. One wave = one chunk.
__global__ void convw_kernel(const float* __restrict__ W1, const float* __restrict__ W2,
                             short* __restrict__ D1, short* __restrict__ D2) {
    size_t t = (size_t)blockIdx.x * 256 + threadIdx.x;
    const size_t PER = (size_t)NEXP * HD * HD / 8;
    const float* src = W1; short* dst = D1;
    if (t >= PER) { t -= PER; src = W2; dst = D2; }
    size_t C = t >> 6;
    int l  = (int)(t & 63);
    int kc = (int)(C & 31);
    int ng = (int)((C >> 5) & 63);
    int ei = (int)(C >> 11);
    int n = ng * 16 + (l & 15);
    int k = kc * 32 + (l >> 4) * 8;
    const float* s = src + ((size_t)ei * HD + n) * HD + k;
    vfloat4 a = *(const vfloat4*)s;
    vfloat4 b = *(const vfloat4*)(s + 4);
    vshort8 o;
    o[0] = bf16r(a.x); o[1] = bf16r(a.y); o[2] = bf16r(a.z); o[3] = bf16r(a.w);
    o[4] = bf16r(b.x); o[5] = bf16r(b.y); o[6] = bf16r(b.z); o[7] = bf16r(b.w);
    *(vshort8*)(dst + t * 8) = o;
}

// --- K6/K7: grouped NT-GEMM, async fragment-ordered staging ----------------
// LDS: sA = smem[0..8191] (16 chunks [g 0..7][s 0..1] x 512 shorts),
//      sB = smem[8192..16383]. Chunk = 1KB, lane l's 16B at base + l*16.
// MODE 0: A rows gathered via pair_token (per-lane global addr);
//         epilogue relu(acc+b1) -> LDS tile -> chunk-ordered h1sw.
// MODE 1: A = h1sw chunks (contiguous); epilogue atomicAdd out += w*(acc+b2).
template <int MODE>
__global__ __launch_bounds__(256, 4) void moe_gemm(
    const short* __restrict__ A, const short* __restrict__ Bw,
    const float* __restrict__ bias, const int* __restrict__ pair_token,
    const float* __restrict__ pair_w, const int* __restrict__ offs,
    short* __restrict__ h1sw_out, float* __restrict__ out) {
    __shared__ short smem[(MODE == 0) ? (BM * EP_LDSW) : (2 * BM * BK)];

    const int row0 = blockIdx.x * BM;
    const int total = offs[NEXP];            // multiple of 128
    if (row0 >= total) return;
    int e = 0;
#pragma unroll
    for (int k = 0; k < NEXP - 1; ++k)
        if (offs[e + 1] <= row0) e++;

    const int t = threadIdx.x;
    const int wave = t >> 6, lane = t & 63;
    const int wm = wave >> 1, wn = wave & 1;
    const int quad = lane >> 4, l16 = lane & 15;
    const int colb = blockIdx.y * BN;

    // per-lane global source pointers (at k0 = 0); wave stages groups 2w,2w+1
    const char* agp[2];
    const char* bgp[2];
#pragma unroll
    for (int u = 0; u < 2; ++u) {
        int g = 2 * wave + u;
        if (MODE == 0) {
            int tok = pair_token[row0 + g * 16 + l16];
            agp[u] = (const char*)A + (size_t)tok * (HD * 2) + quad * 16;
        } else {
            agp[u] = (const char*)A + (((size_t)(row0 >> 4) + g) * 32) * 1024 + lane * 16;
        }
        bgp[u] = (const char*)Bw + (((size_t)e * 64 + (colb >> 4) + g) * 32) * 1024 + lane * 16;
    }

    vfloat4 acc[4][4];
#pragma unroll
    for (int i = 0; i < 4; ++i)
#pragma unroll
        for (int j = 0; j < 4; ++j)
            acc[i][j] = (vfloat4){0.f, 0.f, 0.f, 0.f};

    for (int k0 = 0; k0 < HD; k0 += BK) {
        __syncthreads();                     // prev tile's reads complete
        const int kc = k0 >> 5;
#pragma unroll
        for (int u = 0; u < 2; ++u) {
            int g = 2 * wave + u;
            short* la = smem + (g * 2) * 512;
            short* lb = smem + 8192 + (g * 2) * 512;
#pragma unroll
            for (int s = 0; s < 2; ++s) {
                const char* ga = (MODE == 0)
                    ? (agp[u] + (size_t)k0 * 2 + s * 64)
                    : (agp[u] + (size_t)(kc + s) * 1024);
                gld16(ga, la + s * 512);
                gld16(bgp[u] + (size_t)(kc + s) * 1024, lb + s * 512);
            }
        }
        __syncthreads();                     // vmcnt drained before barrier
#pragma unroll
        for (int s = 0; s < 2; ++s) {
            vshort8 af[4], bfr[4];
#pragma unroll
            for (int i = 0; i < 4; ++i)
                af[i] = *(const vshort8*)(smem + ((wm * 4 + i) * 2 + s) * 512 + lane * 8);
#pragma unroll
            for (int j = 0; j < 4; ++j)
                bfr[j] = *(const vshort8*)(smem + 8192 + ((wn * 4 + j) * 2 + s) * 512 + lane * 8);
#pragma unroll
            for (int i = 0; i < 4; ++i)
#pragma unroll
                for (int j = 0; j < 4; ++j)
                    acc[i][j] = __builtin_amdgcn_mfma_f32_16x16x32_bf16(af[i], bfr[j], acc[i][j], 0, 0, 0);
        }
    }

    if (MODE == 0) {
        // epilogue: relu(acc+b1) -> bf16 LDS tile -> chunk-ordered h1sw
        __syncthreads();
#pragma unroll
        for (int j = 0; j < 4; ++j) {
            int col = wn * 64 + j * 16 + l16;
            float bv = bias[e * HD + colb + col];
#pragma unroll
            for (int i = 0; i < 4; ++i) {
                int rl = wm * 64 + i * 16 + quad * 4;
#pragma unroll
                for (int reg = 0; reg < 4; ++reg) {
                    float v = acc[i][j][reg] + bv;
                    v = v > 0.f ? v : 0.f;
                    smem[(rl + reg) * EP_LDSW + col] = bf16r(v);
                }
            }
        }
        __syncthreads();
#pragma unroll
        for (int u = 0; u < 2; ++u) {
            int sgl = 2 * wave + u;
            int lrow = sgl * 16 + l16;
#pragma unroll
            for (int kk = 0; kk < 4; ++kk) {
                vshort8 v = *(const vshort8*)(smem + lrow * EP_LDSW + kk * 32 + quad * 8);
                size_t chunk = ((size_t)((row0 >> 4) + sgl) * 32) + ((colb >> 5) + kk);
                *(vshort8*)(h1sw_out + chunk * 512 + lane * 8) = v;
            }
        }
    } else {
        int tok[4][4]; float wv[4][4];
#pragma unroll
        for (int i = 0; i < 4; ++i)
#pragma unroll
            for (int reg = 0; reg < 4; ++reg) {
                int r = row0 + wm * 64 + i * 16 + quad * 4 + reg;
                tok[i][reg] = pair_token[r];
                wv[i][reg] = pair_w[r];
            }
#pragma unroll
        for (int j = 0; j < 4; ++j) {
            int col = colb + wn * 64 + j * 16 + l16;
            float bv = bias[e * HD + col];
#pragma unroll
            for (int i = 0; i < 4; ++i)
#pragma unroll
                for (int reg = 0; reg < 4; ++reg)
                    if (tok[i][reg] < ZROW)
                        atomicAdd(out + (size_t)tok[i][reg] * HD + col,
                                  wv[i][reg] * (acc[i][j][reg] + bv));
        }
    }
}

// --- Fallback GEMM (R2-style, fp32 B, padded LDS) if ws too small ----------
#define LDSP 72
template <int MODE>
__global__ __launch_bounds__(256) void moe_gemm_fb(
    const short* __restrict__ A, const float* __restrict__ Bw,
    const float* __restrict__ bias, const int* __restrict__ pair_token,
    const float* __restrict__ pair_w, const int* __restrict__ offs,
    short* __restrict__ h1_out, float* __restrict__ out) {
    __shared__ short sA[BM * LDSP];
    __shared__ short sB[BN * LDSP];
    const int row0 = blockIdx.x * BM;
    const int total = offs[NEXP];
    if (row0 >= total) return;
    int e = 0;
#pragma unroll
    for (int k = 0; k < NEXP - 1; ++k)
        if (offs[e + 1] <= row0) e++;
    const int t = threadIdx.x;
    const int wave = t >> 6, lane = t & 63;
    const int wm = wave >> 1, wn = wave & 1;
    const int quad = lane >> 4, l16 = lane & 15;
    const int colb = blockIdx.y * BN;
    const int arow = t >> 3;
    const int acol = (t & 7) * 8;
    const short* aptr[4];
#pragma unroll
    for (int r = 0; r < 4; ++r) {
        int rit = r * 32 + arow;
        int row = (MODE == 0) ? pair_token[row0 + rit] : (row0 + rit);
        aptr[r] = A + (size_t)row * HD + acol;
    }
    const float* bptrf = Bw + (size_t)e * HD * HD +
                         (size_t)(colb + (t >> 4)) * HD + (t & 15) * 4;
    vfloat4 acc[4][4];
#pragma unroll
    for (int i = 0; i < 4; ++i)
#pragma unroll
        for (int j = 0; j < 4; ++j)
            acc[i][j] = (vfloat4){0.f, 0.f, 0.f, 0.f};
    for (int k0 = 0; k0 < HD; k0 += BK) {
        __syncthreads();
#pragma unroll
        for (int r = 0; r < 4; ++r) {
            vshort8 v = *(const vshort8*)(aptr[r] + k0);
            *(vshort8*)(sA + (r * 32 + arow) * LDSP + acol) = v;
        }
#pragma unroll
        for (int j = 0; j < 8; ++j) {
            vfloat4 v = *(const vfloat4*)(bptrf + (size_t)j * 16 * HD + k0);
            vshort4 b;
            b.x = bf16r(v.x); b.y = bf16r(v.y); b.z = bf16r(v.z); b.w = bf16r(v.w);
            *(vshort4*)(sB + (j * 16 + (t >> 4)) * LDSP + (t & 15) * 4) = b;
        }
        __syncthreads();
#pragma unroll
        for (int s = 0; s < 2; ++s) {
            vshort8 af[4], bfr[4];
#pragma unroll
            for (int i = 0; i < 4; ++i)
                af[i] = *(const vshort8*)(sA + (wm * 64 + i * 16 + l16) * LDSP + s * 32 + quad * 8);
#pragma unroll
            for (int i = 0; i < 4; ++i)
                bfr[i] = *(const vshort8*)(sB + (wn * 64 + i * 16 + l16) * LDSP + s * 32 + quad * 8);
#pragma unroll
            for (int i = 0; i < 4; ++i)
#pragma unroll
                for (int j = 0; j < 4; ++j)
                    acc[i][j] = __builtin_amdgcn_mfma_f32_16x16x32_bf16(af[i], bfr[j], acc[i][j], 0, 0, 0);
        }
    }
    if (MODE == 0) {
#pragma unroll
        for (int j = 0; j < 4; ++j) {
            int col = colb + wn * 64 + j * 16 + l16;
            float bv = bias[e * HD + col];
#pragma unroll
            for (int i = 0; i < 4; ++i) {
                int rbase = row0 + wm * 64 + i * 16 + quad * 4;
#pragma unroll
                for (int reg = 0; reg < 4; ++reg) {
                    float v = acc[i][j][reg] + bv;
                    v = v > 0.f ? v : 0.f;
                    h1_out[(size_t)(rbase + reg) * HD + col] = bf16r(v);
                }
            }
        }
    } else {
        int tok[4][4]; float wv[4][4];
#pragma unroll
        for (int i = 0; i < 4; ++i)
#pragma unroll
            for (int reg = 0; reg < 4; ++reg) {
                int r = row0 + wm * 64 + i * 16 + quad * 4 + reg;
                tok[i][reg] = pair_token[r];
                wv[i][reg] = pair_w[r];
            }
#pragma unroll
        for (int j = 0; j < 4; ++j) {
            int col = colb + wn * 64 + j * 16 + l16;
            float bv = bias[e * HD + col];
#pragma unroll
            for (int i = 0; i < 4; ++i)
#pragma unroll
                for (int reg = 0; reg < 4; ++reg)
                    if (tok[i][reg] < ZROW)
                        atomicAdd(out + (size_t)tok[i][reg] * HD + col,
                                  wv[i][reg] * (acc[i][j][reg] + bv));
        }
    }
}

extern "C" void kernel_launch(void* const* d_in, const int* in_sizes, int n_in,
                              void* d_out, int out_size, void* d_ws, size_t ws_size,
                              hipStream_t stream) {
    const float* x  = (const float*)d_in[0];
    const float* rw = (const float*)d_in[1];
    const float* W1 = (const float*)d_in[2];
    const float* b1 = (const float*)d_in[3];
    const float* W2 = (const float*)d_in[4];
    const float* b2 = (const float*)d_in[5];
    float* out   = (float*)d_out;                // [8192,1024] residual+moe
    float* probs = out + (size_t)NTOK * HD;      // [8192,8]

    char* ws = (char*)d_ws;
    short* xb = (short*)ws;            ws += (size_t)(NTOK + 1) * HD * 2;
    short* h1 = (short*)ws;            ws += (size_t)MAXP * HD * 2;
    int*   pair_token = (int*)ws;      ws += MAXP * 4;
    float* pair_w     = (float*)ws;    ws += MAXP * 4;
    int*   counts = (int*)ws;          ws += 256;
    int*   fill   = (int*)ws;          ws += 256;
    int*   offs   = (int*)ws;          ws += 256;
    int2*   tok_top = (int2*)ws;       ws += NTOK * 8;
    float2* tok_w   = (float2*)ws;     ws += NTOK * 8;
    short* w1sw = (short*)ws;          ws += (size_t)NEXP * HD * HD * 2;
    short* w2sw = (short*)ws;          ws += (size_t)NEXP * HD * HD * 2;
    const bool use_sw = ws_size >= (size_t)((char*)ws - (char*)d_ws);

    init_kernel<<<MAXP / 256, 256, 0, stream>>>(counts, fill, pair_token, xb);
    router_kernel<<<NTOK / 32, 256, 0, stream>>>(x, rw, out, xb, probs,
                                                 tok_top, tok_w, counts);
    offsets_kernel<<<1, 64, 0, stream>>>(counts, offs);
    scatter_kernel<<<NTOK / 256, 256, 0, stream>>>(tok_top, tok_w, offs, fill,
                                                   pair_token, pair_w);
    dim3 gg(MAXP / BM, HD / BN);       // 136 x 8; blocks past padded total exit
    if (use_sw) {
        int cg = (int)(2 * ((size_t)NEXP * HD * HD / 8) / 256);   // 8192 blocks
        convw_kernel<<<cg, 256, 0, stream>>>(W1, W2, w1sw, w2sw);
        moe_gemm<0><<<gg, 256, 0, stream>>>(xb, w1sw, b1, pair_token, pair_w, offs, h1, nullptr);
        moe_gemm<1><<<gg, 256, 0, stream>>>(h1, w2sw, b2, pair_token, pair_w, offs, nullptr, out);
    } else {
        moe_gemm_fb<0><<<gg, 256, 0, stream>>>(xb, W1, b1, pair_token, pair_w, offs, h1, nullptr);
        moe_gemm_fb<1><<<gg, 256, 0, stream>>>(h1, W2, b2, pair_token, pair_w, offs, nullptr, out);
    }
}

// Round 4
// 326.232 us; speedup vs baseline: 1.9368x; 1.0311x over previous
//
#include <hip/hip_runtime.h>
#include <hip/hip_bf16.h>

// ---------------------------------------------------------------------------
// FakeFlexOlmoSparseMlp: top-2 MoE over 8 experts, H=1024, 8192 tokens.
// R4: 512-thread (8-wave) GEMM blocks, same 1KB-chunk async staging.
// R3 post-mortem: MfmaUtil 12.3% == MFMA share of the serial per-iter path
// -> no cross-wave latency hiding at 2.4 waves/SIMD. 8 waves/block + lower
// VGPR (acc 4x2/wave) doubles resident waves/CU. offsets_kernel folded into
// scatter/gemm (inline padded prefix over counts).
// ---------------------------------------------------------------------------

#define HD   1024
#define NTOK 8192
#define NEXP 8
#define BM   128
#define BN   128
#define BK   64
#define ZROW 8192     // sentinel row in x_bf16 filled with zeros (pad slots)
#define MAXP 17408    // 16384 pairs + 8*128 max padding = 136 tiles of 128
#define EP_LDSW 136   // epilogue LDS row stride (shorts); 272B = 16B-aligned

typedef __attribute__((ext_vector_type(8))) short  vshort8;
typedef __attribute__((ext_vector_type(4))) short  vshort4;
typedef __attribute__((ext_vector_type(4))) float  vfloat4;

typedef __attribute__((address_space(1))) const unsigned gas_uint;
typedef __attribute__((address_space(3))) unsigned       las_uint;

__device__ __forceinline__ void gld16(const void* g, void* l) {
    // async global->LDS, 16B/lane; LDS dest = wave-uniform base + lane*16
    __builtin_amdgcn_global_load_lds((gas_uint*)g, (las_uint*)l, 16, 0, 0);
}

__device__ __forceinline__ short bf16r(float f) {
    union { float f; unsigned u; } a; a.f = f;
    unsigned r = a.u + 0x7FFFu + ((a.u >> 16) & 1u);   // round-to-nearest-even
    return (short)(r >> 16);
}

// --- K1: zero meta, pair_token -> ZROW sentinel, zero the ZROW row ---------
__global__ void init_kernel(int* counts, int* fill, int* pair_token, short* xb) {
    int i = blockIdx.x * 256 + threadIdx.x;
    if (i < NEXP) { counts[i] = 0; fill[i] = 0; }
    if (i < MAXP) pair_token[i] = ZROW;
    if (i < HD / 8) {
        vshort8 z = {0, 0, 0, 0, 0, 0, 0, 0};
        *(vshort8*)(xb + (size_t)ZROW * HD + i * 8) = z;
    }
}

// --- K2: router fused with residual-copy + bf16 cast -----------------------
__global__ __launch_bounds__(256) void router_kernel(
    const float* __restrict__ x, const float* __restrict__ rw,
    float* __restrict__ out, short* __restrict__ xb,
    float* __restrict__ probs_out, int2* __restrict__ tok_top,
    float2* __restrict__ tok_w, int* __restrict__ counts) {
    __shared__ float rws[NEXP * HD];
    __shared__ int hist[NEXP];
    int t = threadIdx.x;
    if (t < NEXP) hist[t] = 0;
    for (int j = 0; j < 8; ++j) {
        int idx = j * 1024 + t * 4;
        *(vfloat4*)(rws + idx) = *(const vfloat4*)(rw + idx);
    }
    __syncthreads();
    int wave = t >> 6, lane = t & 63;
    for (int it = 0; it < 8; ++it) {
        int token = blockIdx.x * 32 + it * 4 + wave;
        const float* xr = x + (size_t)token * HD;
        float part[NEXP];
#pragma unroll
        for (int e = 0; e < NEXP; ++e) part[e] = 0.f;
        for (int j = 0; j < 4; ++j) {
            int off = j * 256 + lane * 4;
            vfloat4 xv = *(const vfloat4*)(xr + off);
            *(vfloat4*)(out + (size_t)token * HD + off) = xv;   // residual init
            vshort4 bq;
            bq.x = bf16r(xv.x); bq.y = bf16r(xv.y); bq.z = bf16r(xv.z); bq.w = bf16r(xv.w);
            *(vshort4*)(xb + (size_t)token * HD + off) = bq;
#pragma unroll
            for (int e = 0; e < NEXP; ++e) {
                vfloat4 wv = *(const vfloat4*)(rws + e * HD + off);
                part[e] += xv.x * wv.x + xv.y * wv.y + xv.z * wv.z + xv.w * wv.w;
            }
        }
#pragma unroll
        for (int e = 0; e < NEXP; ++e)
            for (int off = 32; off; off >>= 1)
                part[e] += __shfl_xor(part[e], off, 64);
        if (lane == 0) {
            float m = part[0];
#pragma unroll
            for (int e = 1; e < NEXP; ++e) m = fmaxf(m, part[e]);
            float p[NEXP], s = 0.f;
#pragma unroll
            for (int e = 0; e < NEXP; ++e) { p[e] = expf(part[e] - m); s += p[e]; }
            float inv = 1.f / s;
#pragma unroll
            for (int e = 0; e < NEXP; ++e) {
                p[e] *= inv;
                probs_out[(size_t)token * NEXP + e] = p[e];
            }
            int i0 = 0;
#pragma unroll
            for (int e = 1; e < NEXP; ++e) if (p[e] > p[i0]) i0 = e;  // ties -> lowest idx
            int i1 = (i0 == 0) ? 1 : 0;
#pragma unroll
            for (int e = 0; e < NEXP; ++e) if (e != i0 && p[e] > p[i1]) i1 = e;
            float s2 = 1.f / (p[i0] + p[i1]);
            tok_top[token] = make_int2(i0, i1);
            tok_w[token]   = make_float2(p[i0] * s2, p[i1] * s2);
            atomicAdd(&hist[i0], 1);
            atomicAdd(&hist[i1], 1);
        }
    }
    __syncthreads();
    if (t < NEXP) atomicAdd(&counts[t], hist[t]);
}

// --- K3: scatter pairs into expert buckets (inline offsets from counts) ----
__global__ __launch_bounds__(256) void scatter_kernel(
    const int2* __restrict__ tok_top, const float2* __restrict__ tok_w,
    const int* __restrict__ counts, int* fill,
    int* __restrict__ pair_token, float* __restrict__ pair_w) {
    __shared__ int lhist[NEXP];
    __shared__ int lbase[NEXP];
    int t = threadIdx.x;
    if (t < NEXP) lhist[t] = 0;
    __syncthreads();
    int offs[NEXP];
    {
        int acc = 0;
#pragma unroll
        for (int f = 0; f < NEXP; ++f) {
            offs[f] = acc;
            acc += (counts[f] + 127) & ~127;
        }
    }
    int token = blockIdx.x * 256 + t;
    int2 ti = tok_top[token];
    float2 tw = tok_w[token];
    int r0 = atomicAdd(&lhist[ti.x], 1);
    int r1 = atomicAdd(&lhist[ti.y], 1);
    __syncthreads();
    if (t < NEXP) lbase[t] = atomicAdd(&fill[t], lhist[t]);
    __syncthreads();
    int s0 = offs[ti.x] + lbase[ti.x] + r0;
    pair_token[s0] = token; pair_w[s0] = tw.x;
    int s1 = offs[ti.y] + lbase[ti.y] + r1;
    pair_token[s1] = token; pair_w[s1] = tw.y;
}

// --- K4: fp32 W1+W2 -> bf16 in MFMA-fragment chunk order -------------------
// Chunk C = ((e*64 + ng)*32 + kc): 64 lanes x 16B; lane l holds
// W[e][ng*16 + (l&15)][kc*32 + (l>>4)*8 .. +7].
__global__ void convw_kernel(const float* __restrict__ W1, const float* __restrict__ W2,
                             short* __restrict__ D1, short* __restrict__ D2) {
    size_t t = (size_t)blockIdx.x * 256 + threadIdx.x;
    const size_t PER = (size_t)NEXP * HD * HD / 8;
    const float* src = W1; short* dst = D1;
    if (t >= PER) { t -= PER; src = W2; dst = D2; }
    size_t C = t >> 6;
    int l  = (int)(t & 63);
    int kc = (int)(C & 31);
    int ng = (int)((C >> 5) & 63);
    int ei = (int)(C >> 11);
    int n = ng * 16 + (l & 15);
    int k = kc * 32 + (l >> 4) * 8;
    const float* s = src + ((size_t)ei * HD + n) * HD + k;
    vfloat4 a = *(const vfloat4*)s;
    vfloat4 b = *(const vfloat4*)(s + 4);
    vshort8 o;
    o[0] = bf16r(a.x); o[1] = bf16r(a.y); o[2] = bf16r(a.z); o[3] = bf16r(a.w);
    o[4] = bf16r(b.x); o[5] = bf16r(b.y); o[6] = bf16r(b.z); o[7] = bf16r(b.w);
    *(vshort8*)(dst + t * 8) = o;
}

// --- K5/K6: grouped NT-GEMM, 8 waves/block, async fragment staging ---------
// LDS: sA = smem[0..8191] shorts (16 chunks x 512), sB = smem[8192..16383].
// Wave w: rows wm*64 (wm=w>>2), cols wn*32 (wn=w&3); acc[4][2].
// Wave w stages A chunks (g=w, s=0,1) and B chunks (h=w, s=0,1).
// MODE 0: A rows gathered via pair_token; epi relu(acc+b1)->LDS->chunked h1.
// MODE 1: A = chunk-ordered h1; epi atomicAdd out += w*(acc+b2).
template <int MODE>
__global__ __launch_bounds__(512, 4) void moe_gemm(
    const short* __restrict__ A, const short* __restrict__ Bw,
    const float* __restrict__ bias, const int* __restrict__ pair_token,
    const float* __restrict__ pair_w, const int* __restrict__ counts,
    short* __restrict__ h1sw_out, float* __restrict__ out) {
    __shared__ short smem[(MODE == 0) ? (BM * EP_LDSW) : (2 * BM * BK)];

    const int row0 = blockIdx.x * BM;
    // inline padded prefix over counts -> expert id + total
    int e = 0;
    {
        int csum = 0;
#pragma unroll
        for (int f = 0; f < NEXP; ++f) {
            int p = (counts[f] + 127) & ~127;
            if (csum + p <= row0) e = f + 1;
            csum += p;
        }
        if (row0 >= csum) return;       // past padded total
    }

    const int t = threadIdx.x;
    const int wave = t >> 6, lane = t & 63;
    const int wm = wave >> 2, wn = wave & 3;
    const int quad = lane >> 4, l16 = lane & 15;
    const int colb = blockIdx.y * BN;

    // per-lane global source pointers (at k0 = 0)
    const char* agp;
    if (MODE == 0) {
        int tok = pair_token[row0 + wave * 16 + l16];
        agp = (const char*)A + (size_t)tok * (HD * 2) + quad * 16;
    } else {
        agp = (const char*)A + (((size_t)(row0 >> 4) + wave) * 32) * 1024 + lane * 16;
    }
    const char* bgp = (const char*)Bw +
        (((size_t)e * 64 + (colb >> 4) + wave) * 32) * 1024 + lane * 16;

    vfloat4 acc[4][2];
#pragma unroll
    for (int i = 0; i < 4; ++i)
#pragma unroll
        for (int j = 0; j < 2; ++j)
            acc[i][j] = (vfloat4){0.f, 0.f, 0.f, 0.f};

    for (int k0 = 0; k0 < HD; k0 += BK) {
        __syncthreads();                 // prev tile's reads complete
        const int kc = k0 >> 5;
#pragma unroll
        for (int s = 0; s < 2; ++s) {
            const char* ga = (MODE == 0)
                ? (agp + (size_t)k0 * 2 + s * 64)
                : (agp + (size_t)(kc + s) * 1024);
            gld16(ga, smem + (wave * 2 + s) * 512);
            gld16(bgp + (size_t)(kc + s) * 1024, smem + 8192 + (wave * 2 + s) * 512);
        }
        __syncthreads();                 // vmcnt drained before barrier
#pragma unroll
        for (int s = 0; s < 2; ++s) {
            vshort8 af[4], bfr[2];
#pragma unroll
            for (int i = 0; i < 4; ++i)
                af[i] = *(const vshort8*)(smem + ((wm * 4 + i) * 2 + s) * 512 + lane * 8);
#pragma unroll
            for (int j = 0; j < 2; ++j)
                bfr[j] = *(const vshort8*)(smem + 8192 + ((wn * 2 + j) * 2 + s) * 512 + lane * 8);
#pragma unroll
            for (int i = 0; i < 4; ++i)
#pragma unroll
                for (int j = 0; j < 2; ++j)
                    acc[i][j] = __builtin_amdgcn_mfma_f32_16x16x32_bf16(af[i], bfr[j], acc[i][j], 0, 0, 0);
        }
    }

    if (MODE == 0) {
        // epilogue: relu(acc+b1) -> bf16 LDS tile -> chunk-ordered h1sw
        __syncthreads();
#pragma unroll
        for (int j = 0; j < 2; ++j) {
            int col = wn * 32 + j * 16 + l16;
            float bv = bias[e * HD + colb + col];
#pragma unroll
            for (int i = 0; i < 4; ++i) {
                int rl = wm * 64 + i * 16 + quad * 4;
#pragma unroll
                for (int reg = 0; reg < 4; ++reg) {
                    float v = acc[i][j][reg] + bv;
                    v = v > 0.f ? v : 0.f;
                    smem[(rl + reg) * EP_LDSW + col] = bf16r(v);
                }
            }
        }
        __syncthreads();
        int lrow = wave * 16 + l16;
#pragma unroll
        for (int kk = 0; kk < 4; ++kk) {
            vshort8 v = *(const vshort8*)(smem + lrow * EP_LDSW + kk * 32 + quad * 8);
            size_t chunk = ((size_t)((row0 >> 4) + wave) * 32) + ((colb >> 5) + kk);
            *(vshort8*)(h1sw_out + chunk * 512 + lane * 8) = v;
        }
    } else {
        int tok[4][4]; float wv[4][4];
#pragma unroll
        for (int i = 0; i < 4; ++i)
#pragma unroll
            for (int reg = 0; reg < 4; ++reg) {
                int r = row0 + wm * 64 + i * 16 + quad * 4 + reg;
                tok[i][reg] = pair_token[r];
                wv[i][reg] = pair_w[r];
            }
#pragma unroll
        for (int j = 0; j < 2; ++j) {
            int col = colb + wn * 32 + j * 16 + l16;
            float bv = bias[e * HD + col];
#pragma unroll
            for (int i = 0; i < 4; ++i)
#pragma unroll
                for (int reg = 0; reg < 4; ++reg)
                    if (tok[i][reg] < ZROW)
                        atomicAdd(out + (size_t)tok[i][reg] * HD + col,
                                  wv[i][reg] * (acc[i][j][reg] + bv));
        }
    }
}

extern "C" void kernel_launch(void* const* d_in, const int* in_sizes, int n_in,
                              void* d_out, int out_size, void* d_ws, size_t ws_size,
                              hipStream_t stream) {
    const float* x  = (const float*)d_in[0];
    const float* rw = (const float*)d_in[1];
    const float* W1 = (const float*)d_in[2];
    const float* b1 = (const float*)d_in[3];
    const float* W2 = (const float*)d_in[4];
    const float* b2 = (const float*)d_in[5];
    float* out   = (float*)d_out;                // [8192,1024] residual+moe
    float* probs = out + (size_t)NTOK * HD;      // [8192,8]

    char* ws = (char*)d_ws;
    short* xb = (short*)ws;            ws += (size_t)(NTOK + 1) * HD * 2;
    short* h1 = (short*)ws;            ws += (size_t)MAXP * HD * 2;
    int*   pair_token = (int*)ws;      ws += MAXP * 4;
    float* pair_w     = (float*)ws;    ws += MAXP * 4;
    int*   counts = (int*)ws;          ws += 256;
    int*   fill   = (int*)ws;          ws += 256;
    int2*   tok_top = (int2*)ws;       ws += NTOK * 8;
    float2* tok_w   = (float2*)ws;     ws += NTOK * 8;
    short* w1sw = (short*)ws;          ws += (size_t)NEXP * HD * HD * 2;
    short* w2sw = (short*)ws;          ws += (size_t)NEXP * HD * HD * 2;
    (void)ws_size;

    init_kernel<<<MAXP / 256, 256, 0, stream>>>(counts, fill, pair_token, xb);
    router_kernel<<<NTOK / 32, 256, 0, stream>>>(x, rw, out, xb, probs,
                                                 tok_top, tok_w, counts);
    scatter_kernel<<<NTOK / 256, 256, 0, stream>>>(tok_top, tok_w, counts, fill,
                                                   pair_token, pair_w);
    int cg = (int)(2 * ((size_t)NEXP * HD * HD / 8) / 256);   // 8192 blocks
    convw_kernel<<<cg, 256, 0, stream>>>(W1, W2, w1sw, w2sw);
    dim3 gg(MAXP / BM, HD / BN);       // 136 x 8; blocks past padded total exit
    moe_gemm<0><<<gg, 512, 0, stream>>>(xb, w1sw, b1, pair_token, pair_w, counts, h1, nullptr);
    moe_gemm<1><<<gg, 512, 0, stream>>>(h1, w2sw, b2, pair_token, pair_w, counts, nullptr, out);
}